// Round 1
// baseline (379.007 us; speedup 1.0000x reference)
//
#include <hip/hip_runtime.h>
#include <stdint.h>

// GIN forward: B=32, N=1024, D=128, L=2.
// Strategy: bf16 MFMA (16x16x32) for all GEMMs, fp32 accumulate; BN stats fused
// into GEMM epilogues via shfl+LDS+global atomics; h kept transposed [b][d][n]
// in bf16 so MFMA B-fragments read contiguous K from LDS.

#define BB 32
#define NN 1024
#define DD 128
#define RR 32768  // BB*NN

typedef __bf16 bf16_t;
typedef bf16_t bf16x8 __attribute__((ext_vector_type(8)));
typedef float f32x4 __attribute__((ext_vector_type(4)));

__device__ __forceinline__ unsigned short f2b(float f) {
  unsigned u = __float_as_uint(f);
  u += 0x7fff + ((u >> 16) & 1);   // round-to-nearest-even
  return (unsigned short)(u >> 16);
}

// ---------------- K0a: x [b][n][d] f32 -> hT [b][d][n] bf16 ----------------
__global__ __launch_bounds__(256) void k0_xT(const float* __restrict__ x,
                                             unsigned short* __restrict__ hT) {
  const int b = blockIdx.x, nt = blockIdx.y, tid = threadIdx.x;
  __shared__ alignas(16) unsigned short T[128][136];
  const int r = tid >> 1, c0 = (tid & 1) * 64;
  const float* src = x + ((size_t)(b * 8 + nt) * 128 + r) * 128 + c0;
#pragma unroll
  for (int i = 0; i < 64; i += 4) {
    float4 v = *(const float4*)(src + i);
    int c = c0 + i;
    T[c][r] = f2b(v.x); T[c + 1][r] = f2b(v.y);
    T[c + 2][r] = f2b(v.z); T[c + 3][r] = f2b(v.w);
  }
  __syncthreads();
  const int d = tid >> 1, n0 = (tid & 1) * 64;
  unsigned short* dst = hT + ((size_t)b * DD + d) * NN + nt * 128 + n0;
#pragma unroll
  for (int i = 0; i < 64; i += 8)
    *(uint4*)(dst + i) = *(const uint4*)&T[d][n0 + i];
}

// ---------------- K0w: W[l][k][n] f32 -> WT[l][n][k] bf16 ----------------
__global__ __launch_bounds__(256) void k0_wT(const float* __restrict__ W1,
                                             const float* __restrict__ W2,
                                             unsigned short* __restrict__ W1T,
                                             unsigned short* __restrict__ W2T) {
  int idx = blockIdx.x * 256 + threadIdx.x;  // 0..65535
  int w = idx >> 15;
  int rem = idx & 32767;
  int l = rem >> 14;
  int n = (rem >> 7) & 127;
  int k = rem & 127;
  const float* W = w ? W2 : W1;
  unsigned short* WT = w ? W2T : W1T;
  WT[((size_t)l * 128 + n) * 128 + k] = f2b(W[((size_t)l * 128 + k) * 128 + n]);
}

// ---------------- K1: pooled[b][i][d] = sum_j adj[b][i][j] * h[b][j][d] ----
__global__ __launch_bounds__(256) void k1_pool(const float* __restrict__ adj,
                                               const unsigned short* __restrict__ hT,
                                               unsigned short* __restrict__ pooled) {
  const int mt = blockIdx.x, b = blockIdx.y;
  const int tid = threadIdx.x;
  const int wave = tid >> 6, lane = tid & 63;
  const int wr = (wave >> 1) * 64, wc = (wave & 1) * 64;
  const int ln = lane & 15, q = lane >> 4;

  __shared__ alignas(16) unsigned short As[128][40];
  __shared__ alignas(16) unsigned short Bs[128][40];

  const float* adjb = adj + ((size_t)b * NN + mt * 128) * NN;
  const unsigned short* hTb = hT + (size_t)b * DD * NN;

  f32x4 acc[4][4];
  f32x4 zero = {0.f, 0.f, 0.f, 0.f};
#pragma unroll
  for (int i = 0; i < 4; i++)
#pragma unroll
    for (int j = 0; j < 4; j++) acc[i][j] = zero;

  const int rs = tid >> 1;   // 0..127
  const int hs = tid & 1;    // half of 32-wide K chunk

  for (int k0 = 0; k0 < NN; k0 += 32) {
    __syncthreads();
    {  // stage A: adj rows f32 -> bf16
      const float* src = adjb + (size_t)rs * NN + k0 + hs * 16;
      alignas(16) unsigned short t[16];
#pragma unroll
      for (int i = 0; i < 16; i += 4) {
        float4 v = *(const float4*)(src + i);
        t[i] = f2b(v.x); t[i + 1] = f2b(v.y); t[i + 2] = f2b(v.z); t[i + 3] = f2b(v.w);
      }
      *(uint4*)&As[rs][hs * 16] = *(const uint4*)&t[0];
      *(uint4*)&As[rs][hs * 16 + 8] = *(const uint4*)&t[8];
    }
    {  // stage B: hT rows (already bf16, contiguous K)
      const unsigned short* src = hTb + (size_t)rs * NN + k0 + hs * 16;
      *(uint4*)&Bs[rs][hs * 16] = *(const uint4*)(src);
      *(uint4*)&Bs[rs][hs * 16 + 8] = *(const uint4*)(src + 8);
    }
    __syncthreads();
    bf16x8 af[4], bfr[4];
#pragma unroll
    for (int i = 0; i < 4; i++) af[i] = *(const bf16x8*)&As[wr + i * 16 + ln][q * 8];
#pragma unroll
    for (int j = 0; j < 4; j++) bfr[j] = *(const bf16x8*)&Bs[wc + j * 16 + ln][q * 8];
#pragma unroll
    for (int i = 0; i < 4; i++)
#pragma unroll
      for (int j = 0; j < 4; j++)
        acc[i][j] = __builtin_amdgcn_mfma_f32_16x16x32_bf16(af[i], bfr[j], acc[i][j], 0, 0, 0);
  }

  unsigned short* outb = pooled + ((size_t)b * NN + mt * 128) * DD;
#pragma unroll
  for (int i = 0; i < 4; i++) {
    int row = wr + i * 16 + q * 4;
#pragma unroll
    for (int j = 0; j < 4; j++) {
      int col = wc + j * 16 + ln;
#pragma unroll
      for (int r = 0; r < 4; r++)
        outb[(size_t)(row + r) * DD + col] = f2b(acc[i][j][r]);
    }
  }
}

// ---------------- K2: z1 = pooled @ W1 + b1 ; col stats ----------------
__global__ __launch_bounds__(256) void k2_lin(const unsigned short* __restrict__ Ain,
                                              const unsigned short* __restrict__ WT,
                                              const float* __restrict__ bias,
                                              float* __restrict__ Z,
                                              float* __restrict__ gsum,
                                              float* __restrict__ gsq) {
  const int mt = blockIdx.x;
  const int tid = threadIdx.x;
  const int wave = tid >> 6, lane = tid & 63;
  const int wr = (wave >> 1) * 64, wc = (wave & 1) * 64;
  const int ln = lane & 15, q = lane >> 4;

  __shared__ alignas(16) unsigned short As[128][40];
  __shared__ alignas(16) unsigned short Ws[128][136];
  __shared__ float lsum[128], lsq[128];

  if (tid < 128) { lsum[tid] = 0.f; lsq[tid] = 0.f; }
#pragma unroll
  for (int p = 0; p < 8; p++) {  // stage whole WT (n-major)
    int c = tid + p * 256;
    int n = c >> 4, k8 = (c & 15) * 8;
    *(uint4*)&Ws[n][k8] = *(const uint4*)&WT[n * 128 + k8];
  }

  f32x4 acc[4][4];
  f32x4 zero = {0.f, 0.f, 0.f, 0.f};
#pragma unroll
  for (int i = 0; i < 4; i++)
#pragma unroll
    for (int j = 0; j < 4; j++) acc[i][j] = zero;

  const int rs = tid >> 1, hs = tid & 1;
  const size_t row0 = (size_t)mt * 128;

  for (int k0 = 0; k0 < 128; k0 += 32) {
    __syncthreads();
    const unsigned short* src = Ain + (row0 + rs) * 128 + k0 + hs * 16;
    *(uint4*)&As[rs][hs * 16] = *(const uint4*)src;
    *(uint4*)&As[rs][hs * 16 + 8] = *(const uint4*)(src + 8);
    __syncthreads();
    bf16x8 af[4], bfr[4];
#pragma unroll
    for (int i = 0; i < 4; i++) af[i] = *(const bf16x8*)&As[wr + i * 16 + ln][q * 8];
#pragma unroll
    for (int j = 0; j < 4; j++) bfr[j] = *(const bf16x8*)&Ws[wc + j * 16 + ln][k0 + q * 8];
#pragma unroll
    for (int i = 0; i < 4; i++)
#pragma unroll
      for (int j = 0; j < 4; j++)
        acc[i][j] = __builtin_amdgcn_mfma_f32_16x16x32_bf16(af[i], bfr[j], acc[i][j], 0, 0, 0);
  }

  float s1[4] = {0.f, 0.f, 0.f, 0.f}, s2[4] = {0.f, 0.f, 0.f, 0.f};
  float* Zb = Z + row0 * 128;
#pragma unroll
  for (int j = 0; j < 4; j++) {
    int col = wc + j * 16 + ln;
    float bc = bias[col];
#pragma unroll
    for (int i = 0; i < 4; i++) {
      int row = wr + i * 16 + q * 4;
#pragma unroll
      for (int r = 0; r < 4; r++) {
        float v = acc[i][j][r] + bc;
        Zb[(size_t)(row + r) * 128 + col] = v;
        s1[j] += v; s2[j] += v * v;
      }
    }
  }
#pragma unroll
  for (int j = 0; j < 4; j++) {
    s1[j] += __shfl_xor(s1[j], 16); s1[j] += __shfl_xor(s1[j], 32);
    s2[j] += __shfl_xor(s2[j], 16); s2[j] += __shfl_xor(s2[j], 32);
  }
  if (q == 0) {
#pragma unroll
    for (int j = 0; j < 4; j++) {
      atomicAdd(&lsum[wc + j * 16 + ln], s1[j]);
      atomicAdd(&lsq[wc + j * 16 + ln], s2[j]);
    }
  }
  __syncthreads();
  if (tid < 128) atomicAdd(&gsum[tid], lsum[tid]);
  else atomicAdd(&gsq[tid - 128], lsq[tid - 128]);
}

// ------- K3: z2 = relu(BN(z1)) @ W2 + b2 ; col stats (BN fused in A-stage) ---
__global__ __launch_bounds__(256) void k3_lin(const float* __restrict__ Zin,
                                              const float* __restrict__ gsum_in,
                                              const float* __restrict__ gsq_in,
                                              const float* __restrict__ gamma,
                                              const float* __restrict__ beta,
                                              const unsigned short* __restrict__ WT,
                                              const float* __restrict__ bias,
                                              float* __restrict__ Z,
                                              float* __restrict__ gsum,
                                              float* __restrict__ gsq) {
  const int mt = blockIdx.x;
  const int tid = threadIdx.x;
  const int wave = tid >> 6, lane = tid & 63;
  const int wr = (wave >> 1) * 64, wc = (wave & 1) * 64;
  const int ln = lane & 15, q = lane >> 4;

  __shared__ alignas(16) unsigned short As[128][40];
  __shared__ alignas(16) unsigned short Ws[128][136];
  __shared__ float lsum[128], lsq[128];
  __shared__ float nsc[128], nsh[128];

  if (tid < 128) {
    float mean = gsum_in[tid] * (1.f / 32768.f);
    float var = gsq_in[tid] * (1.f / 32768.f) - mean * mean;
    float sc = gamma[tid] * rsqrtf(var + 1e-5f);
    nsc[tid] = sc; nsh[tid] = beta[tid] - mean * sc;
    lsum[tid] = 0.f; lsq[tid] = 0.f;
  }
#pragma unroll
  for (int p = 0; p < 8; p++) {
    int c = tid + p * 256;
    int n = c >> 4, k8 = (c & 15) * 8;
    *(uint4*)&Ws[n][k8] = *(const uint4*)&WT[n * 128 + k8];
  }

  f32x4 acc[4][4];
  f32x4 zero = {0.f, 0.f, 0.f, 0.f};
#pragma unroll
  for (int i = 0; i < 4; i++)
#pragma unroll
    for (int j = 0; j < 4; j++) acc[i][j] = zero;

  const int rs = tid >> 1, hs = tid & 1;
  const size_t row0 = (size_t)mt * 128;

  for (int k0 = 0; k0 < 128; k0 += 32) {
    __syncthreads();
    {
      const float* src = Zin + (row0 + rs) * 128 + k0 + hs * 16;
      alignas(16) unsigned short t[16];
#pragma unroll
      for (int i = 0; i < 16; i += 4) {
        float4 v = *(const float4*)(src + i);
        int c = k0 + hs * 16 + i;
        t[i]     = f2b(fmaxf(fmaf(v.x, nsc[c], nsh[c]), 0.f));
        t[i + 1] = f2b(fmaxf(fmaf(v.y, nsc[c + 1], nsh[c + 1]), 0.f));
        t[i + 2] = f2b(fmaxf(fmaf(v.z, nsc[c + 2], nsh[c + 2]), 0.f));
        t[i + 3] = f2b(fmaxf(fmaf(v.w, nsc[c + 3], nsh[c + 3]), 0.f));
      }
      *(uint4*)&As[rs][hs * 16] = *(const uint4*)&t[0];
      *(uint4*)&As[rs][hs * 16 + 8] = *(const uint4*)&t[8];
    }
    __syncthreads();
    bf16x8 af[4], bfr[4];
#pragma unroll
    for (int i = 0; i < 4; i++) af[i] = *(const bf16x8*)&As[wr + i * 16 + ln][q * 8];
#pragma unroll
    for (int j = 0; j < 4; j++) bfr[j] = *(const bf16x8*)&Ws[wc + j * 16 + ln][k0 + q * 8];
#pragma unroll
    for (int i = 0; i < 4; i++)
#pragma unroll
      for (int j = 0; j < 4; j++)
        acc[i][j] = __builtin_amdgcn_mfma_f32_16x16x32_bf16(af[i], bfr[j], acc[i][j], 0, 0, 0);
  }

  float s1[4] = {0.f, 0.f, 0.f, 0.f}, s2[4] = {0.f, 0.f, 0.f, 0.f};
  float* Zb = Z + row0 * 128;
#pragma unroll
  for (int j = 0; j < 4; j++) {
    int col = wc + j * 16 + ln;
    float bc = bias[col];
#pragma unroll
    for (int i = 0; i < 4; i++) {
      int row = wr + i * 16 + q * 4;
#pragma unroll
      for (int r = 0; r < 4; r++) {
        float v = acc[i][j][r] + bc;
        Zb[(size_t)(row + r) * 128 + col] = v;
        s1[j] += v; s2[j] += v * v;
      }
    }
  }
#pragma unroll
  for (int j = 0; j < 4; j++) {
    s1[j] += __shfl_xor(s1[j], 16); s1[j] += __shfl_xor(s1[j], 32);
    s2[j] += __shfl_xor(s2[j], 16); s2[j] += __shfl_xor(s2[j], 32);
  }
  if (q == 0) {
#pragma unroll
    for (int j = 0; j < 4; j++) {
      atomicAdd(&lsum[wc + j * 16 + ln], s1[j]);
      atomicAdd(&lsq[wc + j * 16 + ln], s2[j]);
    }
  }
  __syncthreads();
  if (tid < 128) atomicAdd(&gsum[tid], lsum[tid]);
  else atomicAdd(&gsq[tid - 128], lsq[tid - 128]);
}

// -------- K4t: h = relu(BN(z2)) -> hT bf16 [b][d][n] (LDS transpose) --------
__global__ __launch_bounds__(256) void k4_bnt(const float* __restrict__ Z,
                                              const float* __restrict__ gsum,
                                              const float* __restrict__ gsq,
                                              const float* __restrict__ gamma,
                                              const float* __restrict__ beta,
                                              unsigned short* __restrict__ hT) {
  const int b = blockIdx.x, nt = blockIdx.y, tid = threadIdx.x;
  __shared__ alignas(16) unsigned short T[128][136];
  __shared__ float nsc[128], nsh[128];
  if (tid < 128) {
    float mean = gsum[tid] * (1.f / 32768.f);
    float var = gsq[tid] * (1.f / 32768.f) - mean * mean;
    float sc = gamma[tid] * rsqrtf(var + 1e-5f);
    nsc[tid] = sc; nsh[tid] = beta[tid] - mean * sc;
  }
  __syncthreads();
  const int r = tid >> 1, c0 = (tid & 1) * 64;
  const float* src = Z + ((size_t)(b * 8 + nt) * 128 + r) * 128 + c0;
#pragma unroll
  for (int i = 0; i < 64; i += 4) {
    float4 v = *(const float4*)(src + i);
    int c = c0 + i;
    T[c][r]     = f2b(fmaxf(fmaf(v.x, nsc[c], nsh[c]), 0.f));
    T[c + 1][r] = f2b(fmaxf(fmaf(v.y, nsc[c + 1], nsh[c + 1]), 0.f));
    T[c + 2][r] = f2b(fmaxf(fmaf(v.z, nsc[c + 2], nsh[c + 2]), 0.f));
    T[c + 3][r] = f2b(fmaxf(fmaf(v.w, nsc[c + 3], nsh[c + 3]), 0.f));
  }
  __syncthreads();
  const int d = tid >> 1, n0 = (tid & 1) * 64;
  unsigned short* dst = hT + ((size_t)b * DD + d) * NN + nt * 128 + n0;
#pragma unroll
  for (int i = 0; i < 64; i += 8)
    *(uint4*)(dst + i) = *(const uint4*)&T[d][n0 + i];
}

// -------- K4e: final h = relu(BN(z2)) -> d_out f32 [b][n][d] --------
__global__ __launch_bounds__(256) void k4_out(const float* __restrict__ Z,
                                              const float* __restrict__ gsum,
                                              const float* __restrict__ gsq,
                                              const float* __restrict__ gamma,
                                              const float* __restrict__ beta,
                                              float* __restrict__ out) {
  const int blk = blockIdx.x, tid = threadIdx.x;
  __shared__ float nsc[128], nsh[128];
  if (tid < 128) {
    float mean = gsum[tid] * (1.f / 32768.f);
    float var = gsq[tid] * (1.f / 32768.f) - mean * mean;
    float sc = gamma[tid] * rsqrtf(var + 1e-5f);
    nsc[tid] = sc; nsh[tid] = beta[tid] - mean * sc;
  }
  __syncthreads();
  const int r = tid >> 1, c0 = (tid & 1) * 64;
  const float* src = Z + ((size_t)blk * 128 + r) * 128 + c0;
  float* dst = out + ((size_t)blk * 128 + r) * 128 + c0;
#pragma unroll
  for (int i = 0; i < 64; i += 4) {
    float4 v = *(const float4*)(src + i);
    int c = c0 + i;
    float4 o;
    o.x = fmaxf(fmaf(v.x, nsc[c], nsh[c]), 0.f);
    o.y = fmaxf(fmaf(v.y, nsc[c + 1], nsh[c + 1]), 0.f);
    o.z = fmaxf(fmaf(v.z, nsc[c + 2], nsh[c + 2]), 0.f);
    o.w = fmaxf(fmaf(v.w, nsc[c + 3], nsh[c + 3]), 0.f);
    *(float4*)(dst + i) = o;
  }
}

extern "C" void kernel_launch(void* const* d_in, const int* in_sizes, int n_in,
                              void* d_out, int out_size, void* d_ws, size_t ws_size,
                              hipStream_t stream) {
  const float* x = (const float*)d_in[0];
  // d_in[1] = padded_nei (unused by reference)
  const float* adj = (const float*)d_in[2];
  const float* W1 = (const float*)d_in[3];
  const float* b1 = (const float*)d_in[4];
  const float* W2 = (const float*)d_in[5];
  const float* b2 = (const float*)d_in[6];
  const float* g_in = (const float*)d_in[7];
  const float* be_in = (const float*)d_in[8];
  const float* g_out = (const float*)d_in[9];
  const float* be_out = (const float*)d_in[10];
  float* out = (float*)d_out;

  char* ws = (char*)d_ws;
  unsigned short* hT = (unsigned short*)ws;                          // 8 MB
  float* z1 = (float*)(ws + 8ull * 1024 * 1024);                     // 16 MB
  float* z2 = (float*)(ws + 24ull * 1024 * 1024);                    // 16 MB
  unsigned short* pooled = (unsigned short*)(ws + 24ull * 1024 * 1024);  // aliases z2 (never live together)
  unsigned short* W1T = (unsigned short*)(ws + 40ull * 1024 * 1024); // 64 KB
  unsigned short* W2T = W1T + 2 * 128 * 128;                         // 64 KB
  float* stats = (float*)(ws + 40ull * 1024 * 1024 + 256 * 1024);    // 4 stages x 256 f32

  hipMemsetAsync(stats, 0, 4 * 256 * sizeof(float), stream);

  k0_xT<<<dim3(32, 8), 256, 0, stream>>>(x, hT);
  k0_wT<<<256, 256, 0, stream>>>(W1, W2, W1T, W2T);

  for (int l = 0; l < 2; l++) {
    float* st_in = stats + (l * 2 + 0) * 256;
    float* st_out = stats + (l * 2 + 1) * 256;
    k1_pool<<<dim3(8, 32), 256, 0, stream>>>(adj, hT, pooled);
    k2_lin<<<256, 256, 0, stream>>>(pooled, W1T + l * 16384, b1 + l * 128, z1,
                                    st_in, st_in + 128);
    k3_lin<<<256, 256, 0, stream>>>(z1, st_in, st_in + 128, g_in + l * 128,
                                    be_in + l * 128, W2T + l * 16384, b2 + l * 128,
                                    z2, st_out, st_out + 128);
    if (l == 0)
      k4_bnt<<<dim3(32, 8), 256, 0, stream>>>(z2, st_out, st_out + 128, g_out,
                                              be_out, hT);
    else
      k4_out<<<256, 256, 0, stream>>>(z2, st_out, st_out + 128, g_out + 128,
                                      be_out + 128, out);
  }
}